// Round 1
// 1154.819 us; speedup vs baseline: 1.0057x; 1.0057x over previous
//
#include <hip/hip_runtime.h>
#include <hip/hip_bf16.h>

// 5-LOD dense-grid trilinear interpolation, 8 lanes per point (1 lane per corner).
// pts: [N,3] fp32 in [0,1); cbL: [res^3, 8] fp32; out: [N,8] fp32 = sum over LODs.
//
// Lane mapping within a group of 8: c bit0 = x-offset (i), bit1 = y (j), bit2 = z (k)
// so lanes (2m, 2m+1) read x-adjacent rows -> 64 B contiguous, wave-coalesced.
//
// MLP restructure (this revision): phase 1 issues ALL 10 scattered float4 loads
// (5 LODs x {lo,hi}), largest LOD first so the HBM-miss latency of cb4/cb3
// overlaps the issue of the L2/L3-hit loads of cb0..cb2. Phase 2 accumulates in
// ascending-LOD order (matches reference summation order). This needs ~56 VGPRs
// of live state; __launch_bounds__(256, 8) keeps us under the 64-VGPR boundary,
// which is the last occupancy step (8 waves/SIMD) on gfx950 — so full MLP at
// unchanged occupancy.

#define FEAT 8

__global__ __launch_bounds__(256, 8) void dense_grid_kernel(
    const float* __restrict__ pts,
    const float* __restrict__ cb0,
    const float* __restrict__ cb1,
    const float* __restrict__ cb2,
    const float* __restrict__ cb3,
    const float* __restrict__ cb4,
    float* __restrict__ out,
    int n)
{
    const int t = blockIdx.x * blockDim.x + threadIdx.x;
    const int pi = t >> 3;       // point index
    const int c  = t & 7;        // corner id
    if (pi >= n) return;

    const int ci = c & 1;         // x offset
    const int cj = (c >> 1) & 1;  // y offset
    const int ck = (c >> 2) & 1;  // z offset

    const float px = pts[3 * pi + 0];
    const float py = pts[3 * pi + 1];
    const float pz = pts[3 * pi + 2];

    const float* cbs[5] = {cb0, cb1, cb2, cb3, cb4};
    const int ress[5] = {16, 32, 64, 128, 256};

    float  w[5];
    float4 lo[5];
    float4 hi[5];

    // ---- Phase 1: address math + issue all 10 loads (L=4 first: longest latency) ----
    #pragma unroll
    for (int i = 0; i < 5; ++i) {
        const int L = 4 - i;
        const int res = ress[L];
        const float* __restrict__ cb = cbs[L];

        const float sx = px * (float)(res - 1);
        const float sy = py * (float)(res - 1);
        const float sz = pz * (float)(res - 1);

        int x0 = (int)floorf(sx); x0 = min(max(x0, 0), res - 2);
        int y0 = (int)floorf(sy); y0 = min(max(y0, 0), res - 2);
        int z0 = (int)floorf(sz); z0 = min(max(z0, 0), res - 2);

        const float fx = sx - (float)x0;
        const float fy = sy - (float)y0;
        const float fz = sz - (float)z0;

        w[L] = (ci ? fx : 1.f - fx) *
               (cj ? fy : 1.f - fy) *
               (ck ? fz : 1.f - fz);

        // row < 256^3 = 16.8M, row*2 fits int32 comfortably.
        const int row = (x0 + ci) + (y0 + cj) * res + (z0 + ck) * res * res;
        const float4* __restrict__ p = (const float4*)cb + (size_t)(row * 2);
        lo[L] = p[0];
        hi[L] = p[1];
    }

    // ---- Phase 2: accumulate (ascending L, matches reference sum order) ----
    float a[8] = {0.f, 0.f, 0.f, 0.f, 0.f, 0.f, 0.f, 0.f};
    #pragma unroll
    for (int L = 0; L < 5; ++L) {
        const float wl = w[L];
        a[0] += wl * lo[L].x; a[1] += wl * lo[L].y;
        a[2] += wl * lo[L].z; a[3] += wl * lo[L].w;
        a[4] += wl * hi[L].x; a[5] += wl * hi[L].y;
        a[6] += wl * hi[L].z; a[7] += wl * hi[L].w;
    }

    // ---- Transpose-reduce across the 8 lanes of this point's group ----
    // Stage xor 4: keep/receive the half selected by lane bit2.
    {
        const bool hi4 = (c & 4) != 0;
        #pragma unroll
        for (int f = 0; f < 4; ++f) {
            const float send = hi4 ? a[f] : a[f + 4];
            const float recv = __shfl_xor(send, 4);
            a[f] = (hi4 ? a[f + 4] : a[f]) + recv;
        }
    }
    // Stage xor 2
    {
        const bool hi2 = (c & 2) != 0;
        #pragma unroll
        for (int f = 0; f < 2; ++f) {
            const float send = hi2 ? a[f] : a[f + 2];
            const float recv = __shfl_xor(send, 2);
            a[f] = (hi2 ? a[f + 2] : a[f]) + recv;
        }
    }
    // Stage xor 1
    {
        const bool hi1 = (c & 1) != 0;
        const float send = hi1 ? a[0] : a[1];
        const float recv = __shfl_xor(send, 1);
        const float result = (hi1 ? a[1] : a[0]) + recv;
        // lane c holds output element c
        out[(long long)pi * FEAT + c] = result;
    }
}

extern "C" void kernel_launch(void* const* d_in, const int* in_sizes, int n_in,
                              void* d_out, int out_size, void* d_ws, size_t ws_size,
                              hipStream_t stream) {
    const float* pts = (const float*)d_in[0];
    const float* cb0 = (const float*)d_in[1];
    const float* cb1 = (const float*)d_in[2];
    const float* cb2 = (const float*)d_in[3];
    const float* cb3 = (const float*)d_in[4];
    const float* cb4 = (const float*)d_in[5];
    float* out = (float*)d_out;

    const int n = in_sizes[0] / 3;
    const long long threads = (long long)n * 8;
    const int block = 256;
    const long long grid = (threads + block - 1) / block;
    dense_grid_kernel<<<(int)grid, block, 0, stream>>>(pts, cb0, cb1, cb2, cb3, cb4, out, n);
}